// Round 5
// baseline (744.240 us; speedup 1.0000x reference)
//
#include <hip/hip_runtime.h>
#include <hip/hip_bf16.h>

// Sizes (fixed by the problem)
#define NH   128        // hidden channels H
#define NR   6          // radial
#define NCOL 390        // 3H + 2*SH
#define TILE_E 128      // edges per tile (one block-iteration)
#define LDK  136        // padded LDS row stride (bf16 elems): 128 + 8
#define NBLK 512        // persistent blocks: 2 per CU

typedef __attribute__((ext_vector_type(8))) short bf16x8;   // 8 bf16 in 4 VGPRs
typedef __attribute__((ext_vector_type(4))) float f32x4;

__device__ __forceinline__ float fast_silu(float v) {
    // v * rcp(1 + exp(-v)) : ~5 VALU ops vs ~14 for exact-division silu.
    return v * __builtin_amdgcn_rcpf(1.0f + __expf(-v));
}

// ---------------------------------------------------------------------------
// Single prep kernel (unchanged — verified in R2/R4).
// Blocks 0..189: node tables (side = b&1, a = b>>1); 3 spin classes share one
// 128-length dot product.
// Blocks 190..317: bf16 copy of lin_w[:, 262:390] -> Wb, row-major [n][k].
// ---------------------------------------------------------------------------
__global__ void prep_all(const float* __restrict__ emb_w,
                         const float* __restrict__ spin_w,
                         const float* __restrict__ spin_b,
                         const float* __restrict__ lin_w,
                         const float* __restrict__ lin_b,
                         float* __restrict__ Ci, float* __restrict__ Cj,
                         __hip_bfloat16* __restrict__ Wb) {
    int b = blockIdx.x;
    int tid = threadIdx.x;                       // 0..127
    if (b >= 190) {
        int idx = (b - 190) * 128 + tid;         // 0..16383
        int n = idx >> 7, k = idx & 127;
        Wb[idx] = __float2bfloat16(lin_w[(size_t)n * NCOL + 262 + k]);
        return;
    }
    int side = b & 1;                            // 0 = i, 1 = j
    int a    = b >> 1;                           // 0..94
    int n    = tid;
    const int col0 = side ? 131 : 0;
    const int cols = side ? 259 : 128;
    const float* wrow = lin_w + (size_t)n * NCOL;
    const float* ew   = emb_w + a * NH;
    float dot = side ? 0.0f : lin_b[n];
    #pragma unroll 8
    for (int k = 0; k < NH; ++k)
        dot += ew[k] * wrow[col0 + k];
    float* dst = (side ? Cj : Ci) + (size_t)(a * 3) * NH + n;
    #pragma unroll
    for (int sc = 0; sc < 3; ++sc) {
        float acc = dot;
        #pragma unroll
        for (int c = 0; c < 3; ++c)
            acc += (spin_w[c * 3 + sc] + spin_b[c]) * wrow[cols + c];
        dst[(size_t)sc * NH] = acc;
    }
}

// ---------------------------------------------------------------------------
// Main fused kernel: persistent blocks, 512 threads (8 waves), ZERO barriers
// in the steady-state loop (one __syncthreads total, after W staging).
//
// Each wave is fully self-contained per tile:
//  - owns edges e_sub..e_sub+15 of the tile
//  - r-phase: lane (lane15=kgrp, quad=edge-group) computes 4 edges x 8 k,
//    writes ONLY this wave's r_lds rows; afrag reads back the same rows ->
//    ordered by per-wave lgkmcnt, no cross-wave dependency.
//  - node classes: lanes 0..15 run the gi/gj -> x,s chain (issued at tile
//    top, consumed ~1500 cyc later), distributed via __shfl. No idx LDS.
//  - epilogue: one store base + immediate offsets; depth-1 gather pipeline.
// Shared state: w_lds (read-only after init) + per-wave r_lds rows.
// LDS: 34816(W) + 34816(r) = 69632 B -> 2 blocks/CU, 16 waves/CU, free-running.
// ---------------------------------------------------------------------------
__global__ __launch_bounds__(512, 4) void fused_main(
        const int*   __restrict__ x,   const int* __restrict__ s,
        const float* __restrict__ rbf,
        const int*   __restrict__ gi,  const int* __restrict__ gj,
        const float* __restrict__ rbf_w, const float* __restrict__ rbf_b,
        const float* __restrict__ Ci,  const float* __restrict__ Cj,
        const __hip_bfloat16* __restrict__ Wb,
        float* __restrict__ out, int E, int ntiles) {
    __shared__ __align__(16) __hip_bfloat16 w_lds[NH * LDK];
    __shared__ __align__(16) __hip_bfloat16 r_lds[TILE_E * LDK];

    const int tid    = threadIdx.x;
    const int wave   = tid >> 6;
    const int lane   = tid & 63;
    const int lane15 = lane & 15;
    const int quad   = lane >> 4;
    const int e_sub  = wave * 16;

    // ---- stage W once: 2048 x 16B chunks by 512 threads ----
    {
        const uint4* src = (const uint4*)Wb;            // 8 bf16 per chunk
        #pragma unroll
        for (int it = 0; it < 4; ++it) {
            int l = it * 512 + tid;                     // 0..2047
            uint4 v = src[l];
            *(uint4*)&w_lds[(l >> 4) * LDK + (l & 15) * 8] = v;
        }
    }

    // ---- register-resident rbf weights: 8 k's for kgrp = lane15 ----
    float wr[8][6];
    float br[8];
    #pragma unroll
    for (int j = 0; j < 8; ++j) {
        int k = lane15 * 8 + j;
        #pragma unroll
        for (int i = 0; i < 6; ++i) wr[j][i] = rbf_w[k * NR + i];
        br[j] = rbf_b[k];
    }

    __syncthreads();        // ONLY barrier: w_lds visible to all waves

    const int t0 = blockIdx.x;
    const int gstride = gridDim.x;

    for (int t = t0; t < ntiles; t += gstride) {
        const int ew0 = t * TILE_E + e_sub;   // this wave's 16-edge base

        // ---- early issue: node-class chain, lanes 0..15 (one edge each) ----
        int civ = 0, cjv = 0;
        if (lane < 16) {
            int e = ew0 + lane; if (e > E - 1) e = E - 1;
            int ii = gi[e], jj = gj[e];
            civ = x[ii] * 3 + s[ii];
            cjv = x[jj] * 3 + s[jj];
        }

        // ---- rbf load: this quad's 4 edges, 96 B contiguous 16B-aligned ----
        const int e4 = ew0 + quad * 4;
        float c[4][6];
        if (e4 + 4 <= E) {
            const float4* q = (const float4*)(rbf + (size_t)e4 * NR);
            float4 q0 = q[0], q1 = q[1], q2 = q[2], q3 = q[3], q4 = q[4], q5 = q[5];
            c[0][0]=q0.x; c[0][1]=q0.y; c[0][2]=q0.z; c[0][3]=q0.w; c[0][4]=q1.x; c[0][5]=q1.y;
            c[1][0]=q1.z; c[1][1]=q1.w; c[1][2]=q2.x; c[1][3]=q2.y; c[1][4]=q2.z; c[1][5]=q2.w;
            c[2][0]=q3.x; c[2][1]=q3.y; c[2][2]=q3.z; c[2][3]=q3.w; c[2][4]=q4.x; c[2][5]=q4.y;
            c[3][0]=q4.z; c[3][1]=q4.w; c[3][2]=q5.x; c[3][3]=q5.y; c[3][4]=q5.z; c[3][5]=q5.w;
        } else {                               // generic tail: clamped per-row
            #pragma unroll
            for (int r = 0; r < 4; ++r) {
                int er = e4 + r; if (er > E - 1) er = E - 1;
                const float* rp = rbf + (size_t)er * NR;
                #pragma unroll
                for (int i = 0; i < 6; ++i) c[r][i] = rp[i];
            }
        }

        // ---- r = silu(rbf @ rbf_w^T + b) -> bf16, wave-local r_lds rows ----
        #pragma unroll
        for (int r = 0; r < 4; ++r) {
            bf16x8 pk;
            #pragma unroll
            for (int j = 0; j < 8; ++j) {
                float a = br[j] + c[r][0] * wr[j][0] + c[r][1] * wr[j][1]
                                + c[r][2] * wr[j][2] + c[r][3] * wr[j][3]
                                + c[r][4] * wr[j][4] + c[r][5] * wr[j][5];
                __hip_bfloat16 h = __float2bfloat16(fast_silu(a));
                pk[j] = *(short*)&h;
            }
            *(bf16x8*)&r_lds[(e_sub + quad * 4 + r) * LDK + lane15 * 8] = pk;
        }

        // ---- afrag: read back OWN wave's rows (lgkmcnt orders w/r) ----
        bf16x8 afrag[4];
        #pragma unroll
        for (int kt = 0; kt < 4; ++kt)
            afrag[kt] = *(const bf16x8*)&r_lds[(e_sub + lane15) * LDK + kt * 32 + quad * 8];

        // ---- class offsets via shuffle (chain issued ~1500 cyc ago) ----
        int cio[4], cjo[4];
        #pragma unroll
        for (int reg = 0; reg < 4; ++reg) {
            cio[reg] = __shfl(civ, quad * 4 + reg, 64) * NH + lane15;
            cjo[reg] = __shfl(cjv, quad * 4 + reg, 64) * NH + lane15;
        }
        float* ob = out + (size_t)e4 * NH + lane15;   // all stores: imm offsets
        const bool full = (e4 + 4 <= E);

        // ---- MFMA + epilogue, depth-1 gather pipeline over nt ----
        float ga[2][4], gb[2][4];
        #pragma unroll
        for (int reg = 0; reg < 4; ++reg) {
            ga[0][reg] = Ci[cio[reg]];
            gb[0][reg] = Cj[cjo[reg]];
        }
        #pragma unroll
        for (int nt = 0; nt < 8; ++nt) {
            const int cur = nt & 1, nxt = cur ^ 1;   // compile-time after unroll
            if (nt < 7) {
                #pragma unroll
                for (int reg = 0; reg < 4; ++reg) {
                    ga[nxt][reg] = Ci[cio[reg] + (nt + 1) * 16];
                    gb[nxt][reg] = Cj[cjo[reg] + (nt + 1) * 16];
                }
            }
            f32x4 acc = {0.f, 0.f, 0.f, 0.f};
            #pragma unroll
            for (int kt = 0; kt < 4; ++kt) {
                bf16x8 bfrag = *(const bf16x8*)&w_lds[(nt * 16 + lane15) * LDK + kt * 32 + quad * 8];
                acc = __builtin_amdgcn_mfma_f32_16x16x32_bf16(afrag[kt], bfrag, acc, 0, 0, 0);
            }
            #pragma unroll
            for (int reg = 0; reg < 4; ++reg) {
                float v = acc[reg] + ga[cur][reg] + gb[cur][reg];
                float sv = fast_silu(v);
                if (full || (e4 + reg < E))
                    __builtin_nontemporal_store(sv, ob + reg * NH + nt * 16);
            }
        }
    }
}

// ---------------------------------------------------------------------------
extern "C" void kernel_launch(void* const* d_in, const int* in_sizes, int n_in,
                              void* d_out, int out_size, void* d_ws, size_t ws_size,
                              hipStream_t stream) {
    const int*   x      = (const int*)  d_in[0];
    const int*   s      = (const int*)  d_in[1];
    const float* rbf    = (const float*)d_in[2];
    const int*   gi     = (const int*)  d_in[3];
    const int*   gj     = (const int*)  d_in[4];
    const float* emb_w  = (const float*)d_in[5];
    const float* spin_w = (const float*)d_in[6];
    const float* spin_b = (const float*)d_in[7];
    const float* rbf_w  = (const float*)d_in[8];
    const float* rbf_b  = (const float*)d_in[9];
    const float* lin_w  = (const float*)d_in[10];
    const float* lin_b  = (const float*)d_in[11];
    const int E = in_sizes[3];

    float* Ci = (float*)d_ws;                         // 285*128 f32
    float* Cj = Ci + 285 * NH;                        // 285*128 f32
    __hip_bfloat16* Wb = (__hip_bfloat16*)(Cj + 285 * NH);  // 128*128 bf16

    prep_all<<<318, 128, 0, stream>>>(emb_w, spin_w, spin_b, lin_w, lin_b, Ci, Cj, Wb);

    int ntiles = (E + TILE_E - 1) / TILE_E;
    int nblk = ntiles < NBLK ? ntiles : NBLK;
    fused_main<<<nblk, 512, 0, stream>>>(x, s, rbf, gi, gj, rbf_w, rbf_b,
                                         Ci, Cj, Wb, (float*)d_out, E, ntiles);
}